// Round 5
// baseline (233.329 us; speedup 1.0000x reference)
//
#include <hip/hip_runtime.h>

// hashNeRF fused forward, MFMA edition, v2 (latency-hiding round).
//
// Verified facts (round 4: passed, absmax == 0.0):
//  - hash == parity(ix)^parity(iy); only HT[0:2,0:4,0:2] (16 floats) read.
//  - fragment layouts: A row=lane&15, k=8*(lane>>4)+e; B col=lane&15, same k;
//    D col=lane&15, row=4*(lane>>4)+reg.
//  - 3-product bf16 split (hi*hi + hi*lo + lo*hi) is accurate enough (absmax 0).
//
// Round-5 changes (vs 78us dispatch, MfmaUtil 15%, VALUBusy 38%, occ ~10%):
//  1. X prefetch software pipeline (the only in-loop global load was exposing
//     ~900cyc HBM latency per tile at 2 waves/SIMD).
//  2. Activations stored in LDS as SPLIT bf16 planes (hi/lo), [16][72] rows
//     (144B pad): read path is ds_read_b128 -> MFMA with zero cvt; LDS
//     traffic per tile halves (28KB->14KB); layout hits the wave-throughput
//     floor (reads 8cyc, writes 4cyc, all 32 banks covered).
//  3. Occupancy 2->3 waves/SIMD: grid 768 (3 blocks/CU), launch_bounds(256,3).

typedef float  f32x4  __attribute__((ext_vector_type(4)));
typedef __bf16 bf16x4 __attribute__((ext_vector_type(4)));
typedef __bf16 bf16x8 __attribute__((ext_vector_type(8)));

#define MFMA16(A, B, C) __builtin_amdgcn_mfma_f32_16x16x32_bf16((A), (B), (C), 0, 0, 0)

__global__ __launch_bounds__(256, 3) void hashnerf_mfma(
    const float* __restrict__ X,
    const float* __restrict__ HT,
    const float* __restrict__ W1, const float* __restrict__ B1,
    const float* __restrict__ W2, const float* __restrict__ B2,
    const float* __restrict__ W3, const float* __restrict__ B3,
    const float* __restrict__ W4, const float* __restrict__ B4,
    float* __restrict__ out, int npts)
{
    __shared__ __align__(16) float  sBias[208];
    __shared__ __align__(16) __bf16 sHh[4][16 * 72];   // hi plane, 144B rows
    __shared__ __align__(16) __bf16 sHl[4][16 * 72];   // lo plane

    const int tid = threadIdx.x;
    if (tid < 64) {
        sBias[tid]       = B1[tid];
        sBias[64 + tid]  = B2[tid];
        sBias[128 + tid] = B3[tid];
    }
    if (tid < 16) sBias[192 + tid] = (tid < 3) ? B4[tid] : 0.0f;
    __syncthreads();

    const int l  = tid & 63;
    const int p  = l & 15;      // point-in-tile (B/D col), A row
    const int g  = l >> 4;      // lane group: K-chunk / D-row-quad selector
    const int wv = tid >> 6;
    __bf16* __restrict__ Hh = sHh[wv];
    __bf16* __restrict__ Hl = sHl[wv];

    // ---- one-time per-wave: weight fragments (A = W^T), hi/lo bf16 split ----
    bf16x8 w1h[4];                       // L1: 32->64, unsplit
#pragma unroll
    for (int t = 0; t < 4; ++t)
#pragma unroll
        for (int e = 0; e < 8; ++e)
            w1h[t][e] = (__bf16)W1[(8 * g + e) * 64 + p + 16 * t];

    bf16x8 w2h[4][2], w2l[4][2], w3h[4][2], w3l[4][2];
#pragma unroll
    for (int t = 0; t < 4; ++t)
#pragma unroll
        for (int s = 0; s < 2; ++s)
#pragma unroll
            for (int e = 0; e < 8; ++e) {
                float w2 = W2[(32 * s + 8 * g + e) * 64 + p + 16 * t];
                __bf16 h2 = (__bf16)w2;
                w2h[t][s][e] = h2; w2l[t][s][e] = (__bf16)(w2 - (float)h2);
                float w3 = W3[(32 * s + 8 * g + e) * 64 + p + 16 * t];
                __bf16 h3 = (__bf16)w3;
                w3h[t][s][e] = h3; w3l[t][s][e] = (__bf16)(w3 - (float)h3);
            }

    bf16x8 w4h[2], w4l[2];               // L4: 64->3 (rows j>=3 zero)
#pragma unroll
    for (int s = 0; s < 2; ++s)
#pragma unroll
        for (int e = 0; e < 8; ++e) {
            float w = (p < 3) ? W4[(32 * s + 8 * g + e) * 3 + p] : 0.0f;
            __bf16 h = (__bf16)w;
            w4h[s][e] = h; w4l[s][e] = (__bf16)(w - (float)h);
        }

    // hash-table constants (the only 16 floats ever used)
    float t0[8], t1[8];
#pragma unroll
    for (int e = 0; e < 8; ++e) { t0[e] = HT[e]; t1[e] = HT[524288 + e]; }

    // this lane's 4 resolution levels (levels 4g..4g+3)
    const float NVA[4] = {16.f, 17.f, 19.f, 21.f};
    const float NVB[4] = {23.f, 25.f, 27.f, 30.f};
    const float NVC[4] = {33.f, 36.f, 40.f, 44.f};
    const float NVD[4] = {48.f, 53.f, 58.f, 64.f};
    float nv4[4];
#pragma unroll
    for (int j = 0; j < 4; ++j)
        nv4[j] = (g == 0) ? NVA[j] : (g == 1) ? NVB[j] : (g == 2) ? NVC[j] : NVD[j];

    // 64->64 layer: read split planes, 24 MFMA, lrelu+split+store back.
    // All reads precede all writes; same-wave DS ops are ordered by lgkmcnt.
    auto mlp_layer = [&](const bf16x8 (&wh)[4][2], const bf16x8 (&wl)[4][2],
                         const float* __restrict__ bofs) {
        f32x4 a2[4];
#pragma unroll
        for (int t = 0; t < 4; ++t)
            a2[t] = *reinterpret_cast<const f32x4*>(&bofs[16 * t + 4 * g]);
#pragma unroll
        for (int s = 0; s < 2; ++s) {
            bf16x8 xh = *reinterpret_cast<const bf16x8*>(&Hh[p * 72 + 32 * s + 8 * g]);
            bf16x8 xl = *reinterpret_cast<const bf16x8*>(&Hl[p * 72 + 32 * s + 8 * g]);
#pragma unroll
            for (int t = 0; t < 4; ++t) {
                a2[t] = MFMA16(wh[t][s], xh, a2[t]);
                a2[t] = MFMA16(wh[t][s], xl, a2[t]);
                a2[t] = MFMA16(wl[t][s], xh, a2[t]);
            }
        }
#pragma unroll
        for (int t = 0; t < 4; ++t) {
            f32x4 v = a2[t];
            bf16x4 hv, lv;
#pragma unroll
            for (int r = 0; r < 4; ++r) {
                v[r] = fmaxf(v[r], 0.01f * v[r]);
                __bf16 h = (__bf16)v[r];
                hv[r] = h;
                lv[r] = (__bf16)(v[r] - (float)h);
            }
            *reinterpret_cast<bf16x4*>(&Hh[p * 72 + 16 * t + 4 * g]) = hv;
            *reinterpret_cast<bf16x4*>(&Hl[p * 72 + 16 * t + 4 * g]) = lv;
        }
    };

    const int wave_global = blockIdx.x * 4 + wv;
    const int nwaves = gridDim.x * 4;
    const int ntiles = (npts + 15) >> 4;
    const float2* X2 = reinterpret_cast<const float2*>(X);

    int tile = wave_global;
    float2 xv = make_float2(0.f, 0.f);
    if (tile < ntiles) xv = X2[min(tile * 16 + p, npts - 1)];

    for (; tile < ntiles; tile += nwaves) {
        // prefetch next tile's X (hides HBM latency under this tile's compute)
        const int nt = tile + nwaves;
        float2 xnext = xv;
        if (nt < ntiles) xnext = X2[min(nt * 16 + p, npts - 1)];

        // ---- encode: this lane produces enc[8g..8g+7] of its point ----
        bf16x8 bh;
#pragma unroll
        for (int j2 = 0; j2 < 4; ++j2) {
            const float nv = nv4[j2];
            const float sx = xv.x * nv, sy = xv.y * nv;
            const float fx = sx - floorf(sx), fy = sy - floorf(sy);
            const unsigned ix = (unsigned)sx, iy = (unsigned)sy;
            const bool px = (ix & 1u) != 0u, py = (iy & 1u) != 0u;
            const bool pz = px != py;
            const float cx = 1.f - fx, cy = 1.f - fy;
            const float q0 = cx * cy, q1 = cx * fy, q2 = fx * cy, q3 = fx * fy;
            float a0 = q0 * t0[0];
            a0 = fmaf(q1, py ? t1[2] : t0[2], a0);
            a0 = fmaf(q2, px ? t1[4] : t0[4], a0);
            a0 = fmaf(q3, pz ? t1[6] : t0[6], a0);
            float a1 = q0 * t0[1];
            a1 = fmaf(q1, py ? t1[3] : t0[3], a1);
            a1 = fmaf(q2, px ? t1[5] : t0[5], a1);
            a1 = fmaf(q3, pz ? t1[7] : t0[7], a1);
            bh[2 * j2]     = (__bf16)a0;
            bh[2 * j2 + 1] = (__bf16)a1;
        }

        // ---- L1: 32 -> 64 (unsplit), lrelu, split-store to planes ----
        f32x4 acc[4];
#pragma unroll
        for (int t = 0; t < 4; ++t) {
            acc[t] = *reinterpret_cast<const f32x4*>(&sBias[16 * t + 4 * g]);
            acc[t] = MFMA16(w1h[t], bh, acc[t]);
        }
#pragma unroll
        for (int t = 0; t < 4; ++t) {
            f32x4 v = acc[t];
            bf16x4 hv, lv;
#pragma unroll
            for (int r = 0; r < 4; ++r) {
                v[r] = fmaxf(v[r], 0.01f * v[r]);
                __bf16 h = (__bf16)v[r];
                hv[r] = h;
                lv[r] = (__bf16)(v[r] - (float)h);
            }
            *reinterpret_cast<bf16x4*>(&Hh[p * 72 + 16 * t + 4 * g]) = hv;
            *reinterpret_cast<bf16x4*>(&Hl[p * 72 + 16 * t + 4 * g]) = lv;
        }

        // ---- L2, L3 ----
        mlp_layer(w2h, w2l, &sBias[64]);
        mlp_layer(w3h, w3l, &sBias[128]);

        // ---- L4: 64 -> 3 (split), relu, store ----
        f32x4 ao = *reinterpret_cast<const f32x4*>(&sBias[192 + 4 * g]);
#pragma unroll
        for (int s = 0; s < 2; ++s) {
            bf16x8 xh = *reinterpret_cast<const bf16x8*>(&Hh[p * 72 + 32 * s + 8 * g]);
            bf16x8 xl = *reinterpret_cast<const bf16x8*>(&Hl[p * 72 + 32 * s + 8 * g]);
            ao = MFMA16(w4h[s], xh, ao);
            ao = MFMA16(w4h[s], xl, ao);
            ao = MFMA16(w4l[s], xh, ao);
        }
        if (g == 0 && tile * 16 + p < npts) {
            float* op = out + (size_t)(tile * 16 + p) * 3;
            op[0] = fmaxf(ao[0], 0.0f);
            op[1] = fmaxf(ao[1], 0.0f);
            op[2] = fmaxf(ao[2], 0.0f);
        }

        xv = xnext;
    }
}

extern "C" void kernel_launch(void* const* d_in, const int* in_sizes, int n_in,
                              void* d_out, int out_size, void* d_ws, size_t ws_size,
                              hipStream_t stream) {
    const float* X  = (const float*)d_in[0];
    const float* HT = (const float*)d_in[1];
    const float* W1 = (const float*)d_in[2];
    const float* B1 = (const float*)d_in[3];
    const float* W2 = (const float*)d_in[4];
    const float* B2 = (const float*)d_in[5];
    const float* W3 = (const float*)d_in[6];
    const float* B3 = (const float*)d_in[7];
    const float* W4 = (const float*)d_in[8];
    const float* B4 = (const float*)d_in[9];
    float* out = (float*)d_out;

    const int npts = in_sizes[0] / 2;
    // 768 blocks x 4 waves: 3 blocks/CU -> 12 waves/CU -> 3 waves/SIMD
    // (reg budget 170 via launch_bounds; measured need ~168 incl. AGPRs).
    hipLaunchKernelGGL(hashnerf_mfma, dim3(768), dim3(256), 0, stream,
                       X, HT, W1, B1, W2, B2, W3, B3, W4, B4, out, npts);
}

// Round 6
// 155.894 us; speedup vs baseline: 1.4967x; 1.4967x over previous
//
#include <hip/hip_runtime.h>

// hashNeRF fused forward, MFMA edition, v3.
//
// Verified facts (round 4: passed, absmax == 0.0, 78us):
//  - hash == parity(ix)^parity(iy); only HT[0:2,0:4,0:2] (16 floats) read.
//  - fragment layouts: A row=lane&15, k=8*(lane>>4)+e; B col=lane&15, same k;
//    D col=lane&15, row=4*(lane>>4)+reg.
//  - 3-product bf16 split (hi*hi + hi*lo + lo*hi) is accurate (absmax 0).
// Round-5 lesson (153us REGRESSION): __launch_bounds__(256,3) capped unified
//  regs at ~170 < the ~230 this weight-resident scheme needs -> VGPR_Count 84,
//  ~530MB/dispatch scratch spill traffic (FETCH 421MB), memory-bound on spills.
// Round-6 change: revert to __launch_bounds__(256) (round-4 no-spill config);
//  KEEP round-5's X-prefetch pipeline + split bf16 hi/lo LDS planes + grid 768.

typedef float  f32x4  __attribute__((ext_vector_type(4)));
typedef __bf16 bf16x4 __attribute__((ext_vector_type(4)));
typedef __bf16 bf16x8 __attribute__((ext_vector_type(8)));

#define MFMA16(A, B, C) __builtin_amdgcn_mfma_f32_16x16x32_bf16((A), (B), (C), 0, 0, 0)

__global__ __launch_bounds__(256) void hashnerf_mfma(
    const float* __restrict__ X,
    const float* __restrict__ HT,
    const float* __restrict__ W1, const float* __restrict__ B1,
    const float* __restrict__ W2, const float* __restrict__ B2,
    const float* __restrict__ W3, const float* __restrict__ B3,
    const float* __restrict__ W4, const float* __restrict__ B4,
    float* __restrict__ out, int npts)
{
    __shared__ __align__(16) float  sBias[208];
    __shared__ __align__(16) __bf16 sHh[4][16 * 72];   // hi plane, 144B rows
    __shared__ __align__(16) __bf16 sHl[4][16 * 72];   // lo plane

    const int tid = threadIdx.x;
    if (tid < 64) {
        sBias[tid]       = B1[tid];
        sBias[64 + tid]  = B2[tid];
        sBias[128 + tid] = B3[tid];
    }
    if (tid < 16) sBias[192 + tid] = (tid < 3) ? B4[tid] : 0.0f;
    __syncthreads();

    const int l  = tid & 63;
    const int p  = l & 15;      // point-in-tile (B/D col), A row
    const int g  = l >> 4;      // lane group: K-chunk / D-row-quad selector
    const int wv = tid >> 6;
    __bf16* __restrict__ Hh = sHh[wv];
    __bf16* __restrict__ Hl = sHl[wv];

    // ---- one-time per-wave: weight fragments (A = W^T), hi/lo bf16 split ----
    bf16x8 w1h[4];                       // L1: 32->64, unsplit
#pragma unroll
    for (int t = 0; t < 4; ++t)
#pragma unroll
        for (int e = 0; e < 8; ++e)
            w1h[t][e] = (__bf16)W1[(8 * g + e) * 64 + p + 16 * t];

    bf16x8 w2h[4][2], w2l[4][2], w3h[4][2], w3l[4][2];
#pragma unroll
    for (int t = 0; t < 4; ++t)
#pragma unroll
        for (int s = 0; s < 2; ++s)
#pragma unroll
            for (int e = 0; e < 8; ++e) {
                float w2 = W2[(32 * s + 8 * g + e) * 64 + p + 16 * t];
                __bf16 h2 = (__bf16)w2;
                w2h[t][s][e] = h2; w2l[t][s][e] = (__bf16)(w2 - (float)h2);
                float w3 = W3[(32 * s + 8 * g + e) * 64 + p + 16 * t];
                __bf16 h3 = (__bf16)w3;
                w3h[t][s][e] = h3; w3l[t][s][e] = (__bf16)(w3 - (float)h3);
            }

    bf16x8 w4h[2], w4l[2];               // L4: 64->3 (rows j>=3 zero)
#pragma unroll
    for (int s = 0; s < 2; ++s)
#pragma unroll
        for (int e = 0; e < 8; ++e) {
            float w = (p < 3) ? W4[(32 * s + 8 * g + e) * 3 + p] : 0.0f;
            __bf16 h = (__bf16)w;
            w4h[s][e] = h; w4l[s][e] = (__bf16)(w - (float)h);
        }

    // hash-table constants (the only 16 floats ever used)
    float t0[8], t1[8];
#pragma unroll
    for (int e = 0; e < 8; ++e) { t0[e] = HT[e]; t1[e] = HT[524288 + e]; }

    // this lane's 4 resolution levels (levels 4g..4g+3)
    const float NVA[4] = {16.f, 17.f, 19.f, 21.f};
    const float NVB[4] = {23.f, 25.f, 27.f, 30.f};
    const float NVC[4] = {33.f, 36.f, 40.f, 44.f};
    const float NVD[4] = {48.f, 53.f, 58.f, 64.f};
    float nv4[4];
#pragma unroll
    for (int j = 0; j < 4; ++j)
        nv4[j] = (g == 0) ? NVA[j] : (g == 1) ? NVB[j] : (g == 2) ? NVC[j] : NVD[j];

    // 64->64 layer: read split planes, 24 MFMA, lrelu+split+store back.
    // All reads precede all writes; same-wave DS ops are ordered by lgkmcnt.
    auto mlp_layer = [&](const bf16x8 (&wh)[4][2], const bf16x8 (&wl)[4][2],
                         const float* __restrict__ bofs) {
        f32x4 a2[4];
#pragma unroll
        for (int t = 0; t < 4; ++t)
            a2[t] = *reinterpret_cast<const f32x4*>(&bofs[16 * t + 4 * g]);
#pragma unroll
        for (int s = 0; s < 2; ++s) {
            bf16x8 xh = *reinterpret_cast<const bf16x8*>(&Hh[p * 72 + 32 * s + 8 * g]);
            bf16x8 xl = *reinterpret_cast<const bf16x8*>(&Hl[p * 72 + 32 * s + 8 * g]);
#pragma unroll
            for (int t = 0; t < 4; ++t) {
                a2[t] = MFMA16(wh[t][s], xh, a2[t]);
                a2[t] = MFMA16(wh[t][s], xl, a2[t]);
                a2[t] = MFMA16(wl[t][s], xh, a2[t]);
            }
        }
#pragma unroll
        for (int t = 0; t < 4; ++t) {
            f32x4 v = a2[t];
            bf16x4 hv, lv;
#pragma unroll
            for (int r = 0; r < 4; ++r) {
                v[r] = fmaxf(v[r], 0.01f * v[r]);
                __bf16 h = (__bf16)v[r];
                hv[r] = h;
                lv[r] = (__bf16)(v[r] - (float)h);
            }
            *reinterpret_cast<bf16x4*>(&Hh[p * 72 + 16 * t + 4 * g]) = hv;
            *reinterpret_cast<bf16x4*>(&Hl[p * 72 + 16 * t + 4 * g]) = lv;
        }
    };

    const int wave_global = blockIdx.x * 4 + wv;
    const int nwaves = gridDim.x * 4;
    const int ntiles = (npts + 15) >> 4;
    const float2* X2 = reinterpret_cast<const float2*>(X);

    int tile = wave_global;
    float2 xv = make_float2(0.f, 0.f);
    if (tile < ntiles) xv = X2[min(tile * 16 + p, npts - 1)];

    for (; tile < ntiles; tile += nwaves) {
        // prefetch next tile's X (hides HBM latency under this tile's compute)
        const int nt = tile + nwaves;
        float2 xnext = xv;
        if (nt < ntiles) xnext = X2[min(nt * 16 + p, npts - 1)];

        // ---- encode: this lane produces enc[8g..8g+7] of its point ----
        bf16x8 bh;
#pragma unroll
        for (int j2 = 0; j2 < 4; ++j2) {
            const float nv = nv4[j2];
            const float sx = xv.x * nv, sy = xv.y * nv;
            const float fx = sx - floorf(sx), fy = sy - floorf(sy);
            const unsigned ix = (unsigned)sx, iy = (unsigned)sy;
            const bool px = (ix & 1u) != 0u, py = (iy & 1u) != 0u;
            const bool pz = px != py;
            const float cx = 1.f - fx, cy = 1.f - fy;
            const float q0 = cx * cy, q1 = cx * fy, q2 = fx * cy, q3 = fx * fy;
            float a0 = q0 * t0[0];
            a0 = fmaf(q1, py ? t1[2] : t0[2], a0);
            a0 = fmaf(q2, px ? t1[4] : t0[4], a0);
            a0 = fmaf(q3, pz ? t1[6] : t0[6], a0);
            float a1 = q0 * t0[1];
            a1 = fmaf(q1, py ? t1[3] : t0[3], a1);
            a1 = fmaf(q2, px ? t1[5] : t0[5], a1);
            a1 = fmaf(q3, pz ? t1[7] : t0[7], a1);
            bh[2 * j2]     = (__bf16)a0;
            bh[2 * j2 + 1] = (__bf16)a1;
        }

        // ---- L1: 32 -> 64 (unsplit), lrelu, split-store to planes ----
        f32x4 acc[4];
#pragma unroll
        for (int t = 0; t < 4; ++t) {
            acc[t] = *reinterpret_cast<const f32x4*>(&sBias[16 * t + 4 * g]);
            acc[t] = MFMA16(w1h[t], bh, acc[t]);
        }
#pragma unroll
        for (int t = 0; t < 4; ++t) {
            f32x4 v = acc[t];
            bf16x4 hv, lv;
#pragma unroll
            for (int r = 0; r < 4; ++r) {
                v[r] = fmaxf(v[r], 0.01f * v[r]);
                __bf16 h = (__bf16)v[r];
                hv[r] = h;
                lv[r] = (__bf16)(v[r] - (float)h);
            }
            *reinterpret_cast<bf16x4*>(&Hh[p * 72 + 16 * t + 4 * g]) = hv;
            *reinterpret_cast<bf16x4*>(&Hl[p * 72 + 16 * t + 4 * g]) = lv;
        }

        // ---- L2, L3 ----
        mlp_layer(w2h, w2l, &sBias[64]);
        mlp_layer(w3h, w3l, &sBias[128]);

        // ---- L4: 64 -> 3 (split), relu, store ----
        f32x4 ao = *reinterpret_cast<const f32x4*>(&sBias[192 + 4 * g]);
#pragma unroll
        for (int s = 0; s < 2; ++s) {
            bf16x8 xh = *reinterpret_cast<const bf16x8*>(&Hh[p * 72 + 32 * s + 8 * g]);
            bf16x8 xl = *reinterpret_cast<const bf16x8*>(&Hl[p * 72 + 32 * s + 8 * g]);
            ao = MFMA16(w4h[s], xh, ao);
            ao = MFMA16(w4h[s], xl, ao);
            ao = MFMA16(w4l[s], xh, ao);
        }
        if (g == 0 && tile * 16 + p < npts) {
            float* op = out + (size_t)(tile * 16 + p) * 3;
            op[0] = fmaxf(ao[0], 0.0f);
            op[1] = fmaxf(ao[1], 0.0f);
            op[2] = fmaxf(ao[2], 0.0f);
        }

        xv = xnext;
    }
}

extern "C" void kernel_launch(void* const* d_in, const int* in_sizes, int n_in,
                              void* d_out, int out_size, void* d_ws, size_t ws_size,
                              hipStream_t stream) {
    const float* X  = (const float*)d_in[0];
    const float* HT = (const float*)d_in[1];
    const float* W1 = (const float*)d_in[2];
    const float* B1 = (const float*)d_in[3];
    const float* W2 = (const float*)d_in[4];
    const float* B2 = (const float*)d_in[5];
    const float* W3 = (const float*)d_in[6];
    const float* B3 = (const float*)d_in[7];
    const float* W4 = (const float*)d_in[8];
    const float* B4 = (const float*)d_in[9];
    float* out = (float*)d_out;

    const int npts = in_sizes[0] / 2;
    // 768 blocks x 4 waves; no launch_bounds min-occupancy cap (round-5 spill
    // lesson). If unified regs land <=170 we get 3 blocks/CU, else 2 + stagger.
    hipLaunchKernelGGL(hashnerf_mfma, dim3(768), dim3(256), 0, stream,
                       X, HT, W1, B1, W2, B2, W3, B3, W4, B4, out, npts);
}

// Round 7
// 153.382 us; speedup vs baseline: 1.5212x; 1.0164x over previous
//
#include <hip/hip_runtime.h>

// hashNeRF fused forward, MFMA edition, v4 (2-tile ILP + bank fix).
//
// Verified facts (rounds 4/6: passed, absmax == 0.0, 78us):
//  - hash == parity(ix)^parity(iy); only HT[0:2,0:4,0:2] (16 floats) read.
//  - fragment layouts: A row=lane&15, k=8*(lane>>4)+e; B col=lane&15, same k;
//    D col=lane&15, row=4*(lane>>4)+reg.
//  - 3-product bf16 split (hi*hi + hi*lo + lo*hi) is accurate (absmax 0).
// Round-5 lesson: launch_bounds reg cap -> 530MB spill traffic. Keep uncapped.
// Round-6 lesson: X-prefetch + read-path cvt removal bought ZERO (78us flat,
//  busy-sum ~56%, occ ~10%) -> single serial chain per wave is the limiter.
// Round-7 changes:
//  1. TWO tiles in flight per wave (A/B interleaved at source): independent
//     MFMA chains + staggered LDS round trips fill the ~44% stall cycles.
//  2. LDS row stride 72 -> 88 elems (176B = 44dw = 12 mod 32, gcd(12,32)=4:
//     8 distinct start banks x2 lanes = 2-way = free; 16B aligned): fixes the
//     4.7M bank-conflict cycles from the stride-4 layout.

typedef float  f32x4  __attribute__((ext_vector_type(4)));
typedef __bf16 bf16x4 __attribute__((ext_vector_type(4)));
typedef __bf16 bf16x8 __attribute__((ext_vector_type(8)));

#define MFMA16(A, B, C) __builtin_amdgcn_mfma_f32_16x16x32_bf16((A), (B), (C), 0, 0, 0)

#define HSTRIDE 88

__global__ __launch_bounds__(256) void hashnerf_mfma(
    const float* __restrict__ X,
    const float* __restrict__ HT,
    const float* __restrict__ W1, const float* __restrict__ B1,
    const float* __restrict__ W2, const float* __restrict__ B2,
    const float* __restrict__ W3, const float* __restrict__ B3,
    const float* __restrict__ W4, const float* __restrict__ B4,
    float* __restrict__ out, int npts)
{
    __shared__ __align__(16) float  sBias[208];
    __shared__ __align__(16) __bf16 sHh[4][2][16 * HSTRIDE];   // [wave][tile-slot]
    __shared__ __align__(16) __bf16 sHl[4][2][16 * HSTRIDE];

    const int tid = threadIdx.x;
    if (tid < 64) {
        sBias[tid]       = B1[tid];
        sBias[64 + tid]  = B2[tid];
        sBias[128 + tid] = B3[tid];
    }
    if (tid < 16) sBias[192 + tid] = (tid < 3) ? B4[tid] : 0.0f;
    __syncthreads();

    const int l  = tid & 63;
    const int p  = l & 15;      // point-in-tile (B/D col), A row
    const int g  = l >> 4;      // lane group: K-chunk / D-row-quad selector
    const int wv = tid >> 6;
    __bf16* __restrict__ HhA = sHh[wv][0];
    __bf16* __restrict__ HlA = sHl[wv][0];
    __bf16* __restrict__ HhB = sHh[wv][1];
    __bf16* __restrict__ HlB = sHl[wv][1];

    // ---- one-time per-wave: weight fragments (A = W^T), hi/lo bf16 split ----
    bf16x8 w1h[4];                       // L1: 32->64, unsplit
#pragma unroll
    for (int t = 0; t < 4; ++t)
#pragma unroll
        for (int e = 0; e < 8; ++e)
            w1h[t][e] = (__bf16)W1[(8 * g + e) * 64 + p + 16 * t];

    bf16x8 w2h[4][2], w2l[4][2], w3h[4][2], w3l[4][2];
#pragma unroll
    for (int t = 0; t < 4; ++t)
#pragma unroll
        for (int s = 0; s < 2; ++s)
#pragma unroll
            for (int e = 0; e < 8; ++e) {
                float w2 = W2[(32 * s + 8 * g + e) * 64 + p + 16 * t];
                __bf16 h2 = (__bf16)w2;
                w2h[t][s][e] = h2; w2l[t][s][e] = (__bf16)(w2 - (float)h2);
                float w3 = W3[(32 * s + 8 * g + e) * 64 + p + 16 * t];
                __bf16 h3 = (__bf16)w3;
                w3h[t][s][e] = h3; w3l[t][s][e] = (__bf16)(w3 - (float)h3);
            }

    bf16x8 w4h[2], w4l[2];               // L4: 64->3 (rows j>=3 zero)
#pragma unroll
    for (int s = 0; s < 2; ++s)
#pragma unroll
        for (int e = 0; e < 8; ++e) {
            float w = (p < 3) ? W4[(32 * s + 8 * g + e) * 3 + p] : 0.0f;
            __bf16 h = (__bf16)w;
            w4h[s][e] = h; w4l[s][e] = (__bf16)(w - (float)h);
        }

    // hash-table constants (the only 16 floats ever used)
    float t0[8], t1[8];
#pragma unroll
    for (int e = 0; e < 8; ++e) { t0[e] = HT[e]; t1[e] = HT[524288 + e]; }

    // this lane's 4 resolution levels (levels 4g..4g+3)
    const float NVA[4] = {16.f, 17.f, 19.f, 21.f};
    const float NVB[4] = {23.f, 25.f, 27.f, 30.f};
    const float NVC[4] = {33.f, 36.f, 40.f, 44.f};
    const float NVD[4] = {48.f, 53.f, 58.f, 64.f};
    float nv4[4];
#pragma unroll
    for (int j = 0; j < 4; ++j)
        nv4[j] = (g == 0) ? NVA[j] : (g == 1) ? NVB[j] : (g == 2) ? NVC[j] : NVD[j];

    // encode: lane produces enc[8g..8g+7] of its point (bit-exact vs reference)
    auto encode = [&](float2 xv) -> bf16x8 {
        bf16x8 bh;
#pragma unroll
        for (int j2 = 0; j2 < 4; ++j2) {
            const float nv = nv4[j2];
            const float sx = xv.x * nv, sy = xv.y * nv;
            const float fx = sx - floorf(sx), fy = sy - floorf(sy);
            const unsigned ix = (unsigned)sx, iy = (unsigned)sy;
            const bool px = (ix & 1u) != 0u, py = (iy & 1u) != 0u;
            const bool pz = px != py;
            const float cx = 1.f - fx, cy = 1.f - fy;
            const float q0 = cx * cy, q1 = cx * fy, q2 = fx * cy, q3 = fx * fy;
            float a0 = q0 * t0[0];
            a0 = fmaf(q1, py ? t1[2] : t0[2], a0);
            a0 = fmaf(q2, px ? t1[4] : t0[4], a0);
            a0 = fmaf(q3, pz ? t1[6] : t0[6], a0);
            float a1 = q0 * t0[1];
            a1 = fmaf(q1, py ? t1[3] : t0[3], a1);
            a1 = fmaf(q2, px ? t1[5] : t0[5], a1);
            a1 = fmaf(q3, pz ? t1[7] : t0[7], a1);
            bh[2 * j2]     = (__bf16)a0;
            bh[2 * j2 + 1] = (__bf16)a1;
        }
        return bh;
    };

    // lrelu + hi/lo split + store to planes
    auto split_store = [&](f32x4 (&a2)[4], __bf16* __restrict__ Hh_,
                           __bf16* __restrict__ Hl_) {
#pragma unroll
        for (int t = 0; t < 4; ++t) {
            f32x4 v = a2[t];
            bf16x4 hv, lv;
#pragma unroll
            for (int r = 0; r < 4; ++r) {
                v[r] = fmaxf(v[r], 0.01f * v[r]);
                __bf16 h = (__bf16)v[r];
                hv[r] = h;
                lv[r] = (__bf16)(v[r] - (float)h);
            }
            *reinterpret_cast<bf16x4*>(&Hh_[p * HSTRIDE + 16 * t + 4 * g]) = hv;
            *reinterpret_cast<bf16x4*>(&Hl_[p * HSTRIDE + 16 * t + 4 * g]) = lv;
        }
    };

    // one 64->64 layer for BOTH tiles, A/B interleaved (8 indep MFMA chains)
    auto layer_pair = [&](const bf16x8 (&wh)[4][2], const bf16x8 (&wl)[4][2],
                          const float* __restrict__ bofs) {
        f32x4 aA[4], aB[4];
#pragma unroll
        for (int t = 0; t < 4; ++t) {
            aA[t] = *reinterpret_cast<const f32x4*>(&bofs[16 * t + 4 * g]);
            aB[t] = aA[t];
        }
#pragma unroll
        for (int s = 0; s < 2; ++s) {
            bf16x8 xhA = *reinterpret_cast<const bf16x8*>(&HhA[p * HSTRIDE + 32 * s + 8 * g]);
            bf16x8 xlA = *reinterpret_cast<const bf16x8*>(&HlA[p * HSTRIDE + 32 * s + 8 * g]);
            bf16x8 xhB = *reinterpret_cast<const bf16x8*>(&HhB[p * HSTRIDE + 32 * s + 8 * g]);
            bf16x8 xlB = *reinterpret_cast<const bf16x8*>(&HlB[p * HSTRIDE + 32 * s + 8 * g]);
#pragma unroll
            for (int t = 0; t < 4; ++t) {
                aA[t] = MFMA16(wh[t][s], xhA, aA[t]);
                aB[t] = MFMA16(wh[t][s], xhB, aB[t]);
                aA[t] = MFMA16(wh[t][s], xlA, aA[t]);
                aB[t] = MFMA16(wh[t][s], xlB, aB[t]);
                aA[t] = MFMA16(wl[t][s], xhA, aA[t]);
                aB[t] = MFMA16(wl[t][s], xhB, aB[t]);
            }
        }
        split_store(aA, HhA, HlA);
        split_store(aB, HhB, HlB);
    };

    const int wave_global = blockIdx.x * 4 + wv;
    const int nw = gridDim.x * 4;               // 2048 waves
    const int ntiles = (npts + 15) >> 4;        // 32768
    const float2* X2 = reinterpret_cast<const float2*>(X);

    int tA = wave_global;
    int tB = wave_global + nw;
    float2 xA = make_float2(0.f, 0.f), xB = xA;
    if (tA < ntiles) xA = X2[min(tA * 16 + p, npts - 1)];
    if (tB < ntiles) xB = X2[min(tB * 16 + p, npts - 1)];

    for (; tA < ntiles; tA += 2 * nw, tB += 2 * nw) {
        // prefetch next pair's X under this pair's compute
        const int nA = tA + 2 * nw, nB = tB + 2 * nw;
        float2 xnA = xA, xnB = xB;
        if (nA < ntiles) xnA = X2[min(nA * 16 + p, npts - 1)];
        if (nB < ntiles) xnB = X2[min(nB * 16 + p, npts - 1)];
        const bool hasB = (tB < ntiles);

        // ---- encode both tiles (two independent chains) ----
        bf16x8 bhA = encode(xA);
        bf16x8 bhB = encode(xB);

        // ---- L1: 32 -> 64 (unsplit), both tiles ----
        f32x4 aA[4], aB[4];
#pragma unroll
        for (int t = 0; t < 4; ++t) {
            aA[t] = *reinterpret_cast<const f32x4*>(&sBias[16 * t + 4 * g]);
            aB[t] = aA[t];
            aA[t] = MFMA16(w1h[t], bhA, aA[t]);
            aB[t] = MFMA16(w1h[t], bhB, aB[t]);
        }
        split_store(aA, HhA, HlA);
        split_store(aB, HhB, HlB);

        // ---- L2, L3 (pairwise interleaved) ----
        layer_pair(w2h, w2l, &sBias[64]);
        layer_pair(w3h, w3l, &sBias[128]);

        // ---- L4: 64 -> 3 (split), both tiles, relu, store ----
        f32x4 oA = *reinterpret_cast<const f32x4*>(&sBias[192 + 4 * g]);
        f32x4 oB = oA;
#pragma unroll
        for (int s = 0; s < 2; ++s) {
            bf16x8 xhA = *reinterpret_cast<const bf16x8*>(&HhA[p * HSTRIDE + 32 * s + 8 * g]);
            bf16x8 xlA = *reinterpret_cast<const bf16x8*>(&HlA[p * HSTRIDE + 32 * s + 8 * g]);
            bf16x8 xhB = *reinterpret_cast<const bf16x8*>(&HhB[p * HSTRIDE + 32 * s + 8 * g]);
            bf16x8 xlB = *reinterpret_cast<const bf16x8*>(&HlB[p * HSTRIDE + 32 * s + 8 * g]);
            oA = MFMA16(w4h[s], xhA, oA);
            oB = MFMA16(w4h[s], xhB, oB);
            oA = MFMA16(w4h[s], xlA, oA);
            oB = MFMA16(w4h[s], xlB, oB);
            oA = MFMA16(w4l[s], xhA, oA);
            oB = MFMA16(w4l[s], xhB, oB);
        }
        if (g == 0 && tA * 16 + p < npts) {
            float* op = out + (size_t)(tA * 16 + p) * 3;
            op[0] = fmaxf(oA[0], 0.0f);
            op[1] = fmaxf(oA[1], 0.0f);
            op[2] = fmaxf(oA[2], 0.0f);
        }
        if (g == 0 && hasB && tB * 16 + p < npts) {
            float* op = out + (size_t)(tB * 16 + p) * 3;
            op[0] = fmaxf(oB[0], 0.0f);
            op[1] = fmaxf(oB[1], 0.0f);
            op[2] = fmaxf(oB[2], 0.0f);
        }

        xA = xnA; xB = xnB;
    }
}

extern "C" void kernel_launch(void* const* d_in, const int* in_sizes, int n_in,
                              void* d_out, int out_size, void* d_ws, size_t ws_size,
                              hipStream_t stream) {
    const float* X  = (const float*)d_in[0];
    const float* HT = (const float*)d_in[1];
    const float* W1 = (const float*)d_in[2];
    const float* B1 = (const float*)d_in[3];
    const float* W2 = (const float*)d_in[4];
    const float* B2 = (const float*)d_in[5];
    const float* W3 = (const float*)d_in[6];
    const float* B3 = (const float*)d_in[7];
    const float* W4 = (const float*)d_in[8];
    const float* B4 = (const float*)d_in[9];
    float* out = (float*)d_out;

    const int npts = in_sizes[0] / 2;
    // 512 blocks x 4 waves = 2048 waves; 2 tiles/wave-iter -> 8 pair-iters,
    // zero tail. ~46KB LDS/block; no launch_bounds reg cap (round-5 lesson).
    hipLaunchKernelGGL(hashnerf_mfma, dim3(512), dim3(256), 0, stream,
                       X, HT, W1, B1, W2, B2, W3, B3, W4, B4, out, npts);
}

// Round 8
// 128.051 us; speedup vs baseline: 1.8222x; 1.1978x over previous
//
#include <hip/hip_runtime.h>

// hashNeRF fused forward, MFMA edition, v5 (pure-bf16 footprint round).
//
// Verified: hash == parity(ix)^parity(iy), only HT[0:2,0:4,0:2] read; fragment
// layouts A row=lane&15 k=8*(lane>>4)+e / B col=lane&15 / D col=lane&15
// row=4*(lane>>4)+reg (absmax 0.0 in rounds 2-7).
// Round-7 lesson: 3-product split => ~250-290 unified regs => 1 wave/SIMD =>
// all DS/MFMA/VALU latency exposed (39% stall, MfmaUtil 17%). Split cannot
// coexist with occupancy. This round: PURE BF16 (no hi/lo anywhere):
//   - weights 88 VGPR (was 152), total ~160 -> target 3 waves/SIMD
//   - 22 MFMA/tile (was 58), split VALU gone, single LDS activation plane
//   - numerics: bf16 rounding at 3 layer boundaries; predicted absmax 1e-3..6e-3
//     (precision-threshold probe; everything else unchanged).

typedef float  f32x4  __attribute__((ext_vector_type(4)));
typedef __bf16 bf16x4 __attribute__((ext_vector_type(4)));
typedef __bf16 bf16x8 __attribute__((ext_vector_type(8)));

#define MFMA16(A, B, C) __builtin_amdgcn_mfma_f32_16x16x32_bf16((A), (B), (C), 0, 0, 0)

#define HSTRIDE 72   // bf16 elems; 144B rows, every row 16B-aligned

__global__ __launch_bounds__(256) void hashnerf_mfma(
    const float* __restrict__ X,
    const float* __restrict__ HT,
    const float* __restrict__ W1, const float* __restrict__ B1,
    const float* __restrict__ W2, const float* __restrict__ B2,
    const float* __restrict__ W3, const float* __restrict__ B3,
    const float* __restrict__ W4, const float* __restrict__ B4,
    float* __restrict__ out, int npts)
{
    __shared__ __align__(16) float  sBias[208];
    __shared__ __align__(16) __bf16 sHh[4][16 * HSTRIDE];

    const int tid = threadIdx.x;
    if (tid < 64) {
        sBias[tid]       = B1[tid];
        sBias[64 + tid]  = B2[tid];
        sBias[128 + tid] = B3[tid];
    }
    if (tid < 16) sBias[192 + tid] = (tid < 3) ? B4[tid] : 0.0f;
    __syncthreads();

    const int l  = tid & 63;
    const int p  = l & 15;      // point-in-tile (B/D col), A row
    const int g  = l >> 4;      // lane group: K-chunk / D-row-quad selector
    const int wv = tid >> 6;
    __bf16* __restrict__ Hh = sHh[wv];

    // ---- one-time per-wave: bf16 weight fragments (A = W^T) ----
    bf16x8 w1h[4];                       // L1: 32->64
#pragma unroll
    for (int t = 0; t < 4; ++t)
#pragma unroll
        for (int e = 0; e < 8; ++e)
            w1h[t][e] = (__bf16)W1[(8 * g + e) * 64 + p + 16 * t];

    bf16x8 w2h[4][2], w3h[4][2];         // L2/L3: 64->64
#pragma unroll
    for (int t = 0; t < 4; ++t)
#pragma unroll
        for (int s = 0; s < 2; ++s)
#pragma unroll
            for (int e = 0; e < 8; ++e) {
                w2h[t][s][e] = (__bf16)W2[(32 * s + 8 * g + e) * 64 + p + 16 * t];
                w3h[t][s][e] = (__bf16)W3[(32 * s + 8 * g + e) * 64 + p + 16 * t];
            }

    bf16x8 w4h[2];                       // L4: 64->3 (rows j>=3 zero)
#pragma unroll
    for (int s = 0; s < 2; ++s)
#pragma unroll
        for (int e = 0; e < 8; ++e)
            w4h[s][e] = (p < 3) ? (__bf16)W4[(32 * s + 8 * g + e) * 3 + p] : (__bf16)0.0f;

    // hash-table constants (the only 16 floats ever used)
    float t0[8], t1[8];
#pragma unroll
    for (int e = 0; e < 8; ++e) { t0[e] = HT[e]; t1[e] = HT[524288 + e]; }

    // this lane's 4 resolution levels (levels 4g..4g+3)
    const float NVA[4] = {16.f, 17.f, 19.f, 21.f};
    const float NVB[4] = {23.f, 25.f, 27.f, 30.f};
    const float NVC[4] = {33.f, 36.f, 40.f, 44.f};
    const float NVD[4] = {48.f, 53.f, 58.f, 64.f};
    float nv4[4];
#pragma unroll
    for (int j = 0; j < 4; ++j)
        nv4[j] = (g == 0) ? NVA[j] : (g == 1) ? NVB[j] : (g == 2) ? NVC[j] : NVD[j];

    // lrelu + bf16 cvt + store one layer's D to the activation plane
    auto act_store = [&](f32x4 (&a)[4]) {
#pragma unroll
        for (int t = 0; t < 4; ++t) {
            bf16x4 hv;
#pragma unroll
            for (int r = 0; r < 4; ++r) {
                float v = fmaxf(a[t][r], 0.01f * a[t][r]);
                hv[r] = (__bf16)v;
            }
            *reinterpret_cast<bf16x4*>(&Hh[p * HSTRIDE + 16 * t + 4 * g]) = hv;
        }
    };

    const int wave_global = blockIdx.x * 4 + wv;
    const int nw = gridDim.x * 4;
    const int ntiles = (npts + 15) >> 4;
    const float2* X2 = reinterpret_cast<const float2*>(X);

    int tile = wave_global;
    float2 xv = make_float2(0.f, 0.f);
    if (tile < ntiles) xv = X2[min(tile * 16 + p, npts - 1)];

    for (; tile < ntiles; tile += nw) {
        const int nt = tile + nw;
        float2 xnext = xv;
        if (nt < ntiles) xnext = X2[min(nt * 16 + p, npts - 1)];

        // ---- encode: lane produces enc[8g..8g+7] of its point ----
        bf16x8 bh;
#pragma unroll
        for (int j2 = 0; j2 < 4; ++j2) {
            const float nv = nv4[j2];
            const float sx = xv.x * nv, sy = xv.y * nv;
            const float fx = sx - floorf(sx), fy = sy - floorf(sy);
            const unsigned ix = (unsigned)sx, iy = (unsigned)sy;
            const bool px = (ix & 1u) != 0u, py = (iy & 1u) != 0u;
            const bool pz = px != py;
            const float cx = 1.f - fx, cy = 1.f - fy;
            const float q0 = cx * cy, q1 = cx * fy, q2 = fx * cy, q3 = fx * fy;
            float a0 = q0 * t0[0];
            a0 = fmaf(q1, py ? t1[2] : t0[2], a0);
            a0 = fmaf(q2, px ? t1[4] : t0[4], a0);
            a0 = fmaf(q3, pz ? t1[6] : t0[6], a0);
            float a1 = q0 * t0[1];
            a1 = fmaf(q1, py ? t1[3] : t0[3], a1);
            a1 = fmaf(q2, px ? t1[5] : t0[5], a1);
            a1 = fmaf(q3, pz ? t1[7] : t0[7], a1);
            bh[2 * j2]     = (__bf16)a0;
            bh[2 * j2 + 1] = (__bf16)a1;
        }

        // ---- L1: 32 -> 64 ----
        f32x4 acc[4];
#pragma unroll
        for (int t = 0; t < 4; ++t) {
            acc[t] = *reinterpret_cast<const f32x4*>(&sBias[16 * t + 4 * g]);
            acc[t] = MFMA16(w1h[t], bh, acc[t]);
        }
        act_store(acc);

        // ---- L2: 64 -> 64 ----
        {
            bf16x8 x0 = *reinterpret_cast<const bf16x8*>(&Hh[p * HSTRIDE + 8 * g]);
            bf16x8 x1 = *reinterpret_cast<const bf16x8*>(&Hh[p * HSTRIDE + 32 + 8 * g]);
#pragma unroll
            for (int t = 0; t < 4; ++t) {
                acc[t] = *reinterpret_cast<const f32x4*>(&sBias[64 + 16 * t + 4 * g]);
                acc[t] = MFMA16(w2h[t][0], x0, acc[t]);
                acc[t] = MFMA16(w2h[t][1], x1, acc[t]);
            }
            act_store(acc);
        }

        // ---- L3: 64 -> 64 ----
        {
            bf16x8 x0 = *reinterpret_cast<const bf16x8*>(&Hh[p * HSTRIDE + 8 * g]);
            bf16x8 x1 = *reinterpret_cast<const bf16x8*>(&Hh[p * HSTRIDE + 32 + 8 * g]);
#pragma unroll
            for (int t = 0; t < 4; ++t) {
                acc[t] = *reinterpret_cast<const f32x4*>(&sBias[128 + 16 * t + 4 * g]);
                acc[t] = MFMA16(w3h[t][0], x0, acc[t]);
                acc[t] = MFMA16(w3h[t][1], x1, acc[t]);
            }
            act_store(acc);
        }

        // ---- L4: 64 -> 3, relu, store ----
        {
            bf16x8 x0 = *reinterpret_cast<const bf16x8*>(&Hh[p * HSTRIDE + 8 * g]);
            bf16x8 x1 = *reinterpret_cast<const bf16x8*>(&Hh[p * HSTRIDE + 32 + 8 * g]);
            f32x4 ao = *reinterpret_cast<const f32x4*>(&sBias[192 + 4 * g]);
            ao = MFMA16(w4h[0], x0, ao);
            ao = MFMA16(w4h[1], x1, ao);
            if (g == 0 && tile * 16 + p < npts) {
                float* op = out + (size_t)(tile * 16 + p) * 3;
                op[0] = fmaxf(ao[0], 0.0f);
                op[1] = fmaxf(ao[1], 0.0f);
                op[2] = fmaxf(ao[2], 0.0f);
            }
        }

        xv = xnext;
    }
}

extern "C" void kernel_launch(void* const* d_in, const int* in_sizes, int n_in,
                              void* d_out, int out_size, void* d_ws, size_t ws_size,
                              hipStream_t stream) {
    const float* X  = (const float*)d_in[0];
    const float* HT = (const float*)d_in[1];
    const float* W1 = (const float*)d_in[2];
    const float* B1 = (const float*)d_in[3];
    const float* W2 = (const float*)d_in[4];
    const float* B2 = (const float*)d_in[5];
    const float* W3 = (const float*)d_in[6];
    const float* B3 = (const float*)d_in[7];
    const float* W4 = (const float*)d_in[8];
    const float* B4 = (const float*)d_in[9];
    float* out = (float*)d_out;

    const int npts = in_sizes[0] / 2;
    // 768 blocks x 4 waves = 3072 waves; ~10.7 tiles/wave. Target 3 blocks/CU
    // via reduced reg footprint (~160); no launch_bounds reg cap (round-5 lesson).
    hipLaunchKernelGGL(hashnerf_mfma, dim3(768), dim3(256), 0, stream,
                       X, HT, W1, B1, W2, B2, W3, B3, W4, B4, out, npts);
}

// Round 9
// 125.420 us; speedup vs baseline: 1.8604x; 1.0210x over previous
//
#include <hip/hip_runtime.h>

// hashNeRF fused forward, MFMA edition, v6: permuted-neuron zero-LDS pipeline.
//
// Verified: hash == parity(ix)^parity(iy), only HT[0:2,0:4,0:2] read; fragment
// layouts A row=lane&15 k=8*(lane>>4)+e / B col=lane&15 / D col=lane&15
// row=4*(lane>>4)+reg; pure bf16 passes with absmax 0.0 (round 8, 44us).
//
// Round-9 change — algebraic re-layout instead of data movement:
// Hidden neurons are an internal permutation, so permute each hidden layer's
// neuron order by  pi(16t+4g+r) = 32(t&1)+4(t>>1)+8g+r.  Then the MFMA D
// accumulator quads ARE the next layer's B fragments:
//     x0 = cvt(acc[0]) || cvt(acc[2]),  x1 = cvt(acc[1]) || cvt(acc[3])
// (k-slot k holds exactly h[k]; checked: e<4 -> rho=4g+e, pi=8g+e=k, etc.)
// So: A fragments keep IDENTITY k-index and permute only the output column
// (W[k][pi(16t+p)], prologue-only); biases staged pre-permuted; L4/epilogue
// unchanged. Inter-layer handoff = lrelu + 8 cvt_pk in-register. ZERO LDS in
// the loop (no bounce, no bank conflicts, no lgkmcnt in the chain).

typedef float  f32x4  __attribute__((ext_vector_type(4)));
typedef __bf16 bf16x8 __attribute__((ext_vector_type(8)));

#define MFMA16(A, B, C) __builtin_amdgcn_mfma_f32_16x16x32_bf16((A), (B), (C), 0, 0, 0)

__global__ __launch_bounds__(256) void hashnerf_mfma(
    const float* __restrict__ X,
    const float* __restrict__ HT,
    const float* __restrict__ W1, const float* __restrict__ B1,
    const float* __restrict__ W2, const float* __restrict__ B2,
    const float* __restrict__ W3, const float* __restrict__ B3,
    const float* __restrict__ W4, const float* __restrict__ B4,
    float* __restrict__ out, int npts)
{
    __shared__ __align__(16) float sBias[208];

    const int tid = threadIdx.x;
    if (tid < 64) {
        // stage biases PERMUTED: phys slot rho holds B[pi(rho)]
        const int pm = 32 * ((tid >> 4) & 1) + 4 * (tid >> 5)
                     + 8 * ((tid >> 2) & 3) + (tid & 3);
        sBias[tid]       = B1[pm];
        sBias[64 + tid]  = B2[pm];
        sBias[128 + tid] = B3[pm];
    }
    if (tid < 16) sBias[192 + tid] = (tid < 3) ? B4[tid] : 0.0f;
    __syncthreads();

    const int l = tid & 63;
    const int p = l & 15;      // point-in-tile (B/D col), A row
    const int g = l >> 4;      // lane group: K-chunk / D-row-quad selector

    // permuted output column for A fragments of W1/W2/W3: pi(16t + p)
    int po[4];
#pragma unroll
    for (int t = 0; t < 4; ++t)
        po[t] = 32 * (t & 1) + 4 * (t >> 1) + 8 * (p >> 2) + (p & 3);

    // ---- one-time per-wave: bf16 weight fragments (A = W^T) ----
    bf16x8 w1h[4];                       // L1: 32->64, out-permuted
#pragma unroll
    for (int t = 0; t < 4; ++t)
#pragma unroll
        for (int e = 0; e < 8; ++e)
            w1h[t][e] = (__bf16)W1[(8 * g + e) * 64 + po[t]];

    bf16x8 w2h[4][2], w3h[4][2];         // L2/L3: 64->64, k identity, out-permuted
#pragma unroll
    for (int t = 0; t < 4; ++t)
#pragma unroll
        for (int s = 0; s < 2; ++s)
#pragma unroll
            for (int e = 0; e < 8; ++e) {
                w2h[t][s][e] = (__bf16)W2[(32 * s + 8 * g + e) * 64 + po[t]];
                w3h[t][s][e] = (__bf16)W3[(32 * s + 8 * g + e) * 64 + po[t]];
            }

    bf16x8 w4h[2];                       // L4: 64->3, k identity, out identity
#pragma unroll
    for (int s = 0; s < 2; ++s)
#pragma unroll
        for (int e = 0; e < 8; ++e)
            w4h[s][e] = (p < 3) ? (__bf16)W4[(32 * s + 8 * g + e) * 3 + p] : (__bf16)0.0f;

    // hash-table constants (the only 16 floats ever used)
    float t0[8], t1[8];
#pragma unroll
    for (int e = 0; e < 8; ++e) { t0[e] = HT[e]; t1[e] = HT[524288 + e]; }

    // this lane's 4 resolution levels (levels 4g..4g+3)
    const float NVA[4] = {16.f, 17.f, 19.f, 21.f};
    const float NVB[4] = {23.f, 25.f, 27.f, 30.f};
    const float NVC[4] = {33.f, 36.f, 40.f, 44.f};
    const float NVD[4] = {48.f, 53.f, 58.f, 64.f};
    float nv4[4];
#pragma unroll
    for (int j = 0; j < 4; ++j)
        nv4[j] = (g == 0) ? NVA[j] : (g == 1) ? NVB[j] : (g == 2) ? NVC[j] : NVD[j];

    // in-register handoff: lrelu + bf16, D quads -> next layer's B fragments
    auto handoff = [&](const f32x4 (&a)[4], bf16x8& x0, bf16x8& x1) {
#pragma unroll
        for (int r = 0; r < 4; ++r) {
            float v0 = fmaxf(a[0][r], 0.01f * a[0][r]);
            float v1 = fmaxf(a[1][r], 0.01f * a[1][r]);
            float v2 = fmaxf(a[2][r], 0.01f * a[2][r]);
            float v3 = fmaxf(a[3][r], 0.01f * a[3][r]);
            x0[r]     = (__bf16)v0;   // k = 8g+r        (phys rho=4g+r,    pi=k)
            x0[4 + r] = (__bf16)v2;   // k = 8g+4+r      (phys rho=32+4g+r, pi=k)
            x1[r]     = (__bf16)v1;   // k = 32+8g+r
            x1[4 + r] = (__bf16)v3;   // k = 32+8g+4+r
        }
    };

    const int wave_global = blockIdx.x * 4 + (tid >> 6);
    const int nw = gridDim.x * 4;
    const int ntiles = (npts + 15) >> 4;
    const float2* X2 = reinterpret_cast<const float2*>(X);

    int tile = wave_global;
    float2 xv = make_float2(0.f, 0.f);
    if (tile < ntiles) xv = X2[min(tile * 16 + p, npts - 1)];

    for (; tile < ntiles; tile += nw) {
        const int nt = tile + nw;
        float2 xnext = xv;
        if (nt < ntiles) xnext = X2[min(nt * 16 + p, npts - 1)];

        // ---- encode: lane produces enc[8g..8g+7] of its point ----
        bf16x8 bh;
#pragma unroll
        for (int j2 = 0; j2 < 4; ++j2) {
            const float nv = nv4[j2];
            const float sx = xv.x * nv, sy = xv.y * nv;
            const float fx = sx - floorf(sx), fy = sy - floorf(sy);
            const unsigned ix = (unsigned)sx, iy = (unsigned)sy;
            const bool px = (ix & 1u) != 0u, py = (iy & 1u) != 0u;
            const bool pz = px != py;
            const float cx = 1.f - fx, cy = 1.f - fy;
            const float q0 = cx * cy, q1 = cx * fy, q2 = fx * cy, q3 = fx * fy;
            float a0 = q0 * t0[0];
            a0 = fmaf(q1, py ? t1[2] : t0[2], a0);
            a0 = fmaf(q2, px ? t1[4] : t0[4], a0);
            a0 = fmaf(q3, pz ? t1[6] : t0[6], a0);
            float a1 = q0 * t0[1];
            a1 = fmaf(q1, py ? t1[3] : t0[3], a1);
            a1 = fmaf(q2, px ? t1[5] : t0[5], a1);
            a1 = fmaf(q3, pz ? t1[7] : t0[7], a1);
            bh[2 * j2]     = (__bf16)a0;
            bh[2 * j2 + 1] = (__bf16)a1;
        }

        // ---- L1: 32 -> 64 (out-permuted) ----
        f32x4 acc[4];
#pragma unroll
        for (int t = 0; t < 4; ++t) {
            acc[t] = *reinterpret_cast<const f32x4*>(&sBias[16 * t + 4 * g]);
            acc[t] = MFMA16(w1h[t], bh, acc[t]);
        }
        bf16x8 x0, x1;
        handoff(acc, x0, x1);

        // ---- L2: 64 -> 64 ----
#pragma unroll
        for (int t = 0; t < 4; ++t) {
            acc[t] = *reinterpret_cast<const f32x4*>(&sBias[64 + 16 * t + 4 * g]);
            acc[t] = MFMA16(w2h[t][0], x0, acc[t]);
            acc[t] = MFMA16(w2h[t][1], x1, acc[t]);
        }
        handoff(acc, x0, x1);

        // ---- L3: 64 -> 64 ----
#pragma unroll
        for (int t = 0; t < 4; ++t) {
            acc[t] = *reinterpret_cast<const f32x4*>(&sBias[128 + 16 * t + 4 * g]);
            acc[t] = MFMA16(w3h[t][0], x0, acc[t]);
            acc[t] = MFMA16(w3h[t][1], x1, acc[t]);
        }
        handoff(acc, x0, x1);

        // ---- L4: 64 -> 3, relu, store ----
        {
            f32x4 ao = *reinterpret_cast<const f32x4*>(&sBias[192 + 4 * g]);
            ao = MFMA16(w4h[0], x0, ao);
            ao = MFMA16(w4h[1], x1, ao);
            if (g == 0 && tile * 16 + p < npts) {
                float* op = out + (size_t)(tile * 16 + p) * 3;
                op[0] = fmaxf(ao[0], 0.0f);
                op[1] = fmaxf(ao[1], 0.0f);
                op[2] = fmaxf(ao[2], 0.0f);
            }
        }

        xv = xnext;
    }
}

extern "C" void kernel_launch(void* const* d_in, const int* in_sizes, int n_in,
                              void* d_out, int out_size, void* d_ws, size_t ws_size,
                              hipStream_t stream) {
    const float* X  = (const float*)d_in[0];
    const float* HT = (const float*)d_in[1];
    const float* W1 = (const float*)d_in[2];
    const float* B1 = (const float*)d_in[3];
    const float* W2 = (const float*)d_in[4];
    const float* B2 = (const float*)d_in[5];
    const float* W3 = (const float*)d_in[6];
    const float* B3 = (const float*)d_in[7];
    const float* W4 = (const float*)d_in[8];
    const float* B4 = (const float*)d_in[9];
    float* out = (float*)d_out;

    const int npts = in_sizes[0] / 2;
    // 768 blocks x 4 waves = 3072 waves, ~10.7 tiles/wave; target ~165 VGPR
    // -> 3 waves/SIMD (no launch_bounds reg cap: round-5 spill lesson).
    hipLaunchKernelGGL(hashnerf_mfma, dim3(768), dim3(256), 0, stream,
                       X, HT, W1, B1, W2, B2, W3, B3, W4, B4, out, npts);
}